// Round 1
// baseline (476.263 us; speedup 1.0000x reference)
//
#include <hip/hip_runtime.h>
#include <stdint.h>

typedef short short8 __attribute__((ext_vector_type(8)));
typedef float floatx4 __attribute__((ext_vector_type(4)));

#define MFMA16(a, b, c) __builtin_amdgcn_mfma_f32_16x16x32_bf16((a), (b), (c), 0, 0, 0)

__device__ __forceinline__ unsigned short f2bf(float f) {
    union { float f; unsigned u; } v; v.f = f;
    unsigned u = v.u;
    unsigned r = (u + 0x7FFFu + ((u >> 16) & 1u)) >> 16;
    return (unsigned short)r;
}

// ---------------------------------------------------------------------------
// prep: convert weights to bf16; pad W_w [256,131] -> [256,160] with zeros
// ---------------------------------------------------------------------------
__global__ void k_prep(const float* th, const float* ph, const float* gw, const float* Ww,
                       unsigned short* TW, unsigned short* PW, unsigned short* GW,
                       unsigned short* Wp) {
    int i = blockIdx.x * 256 + threadIdx.x;
    if (i < 32768) {
        TW[i] = f2bf(th[i]);
    } else if (i < 65536) {
        PW[i - 32768] = f2bf(ph[i - 32768]);
    } else if (i < 98304) {
        GW[i - 65536] = f2bf(gw[i - 65536]);
    } else if (i < 98304 + 256 * 160) {
        int j = i - 98304;
        int oc = j / 160, k = j - oc * 160;
        Wp[j] = (k < 131) ? f2bf(Ww[oc * 131 + k]) : (unsigned short)0;
    }
}

// ---------------------------------------------------------------------------
// pool: xp[n][c][t][hd][wd] = sum_{3x3 window, stride2, pad1}(x)/9
// ---------------------------------------------------------------------------
__global__ void k_pool(const float* __restrict__ x, float* __restrict__ xp) {
    int e = blockIdx.x * 256 + threadIdx.x;           // < 2*256*4096
    int wd = e & 31, hd = (e >> 5) & 31, t = (e >> 10) & 3, c = (e >> 12) & 255, n = e >> 20;
    const float* base = x + (((size_t)(n * 256 + c) * 4 + t) << 12);
    int h0 = 2 * hd - 1, w0 = 2 * wd - 1;
    float s = 0.f;
    #pragma unroll
    for (int dh = 0; dh < 3; ++dh) {
        int h = h0 + dh;
        if ((unsigned)h < 64u) {
            const float* row = base + h * 64;
            #pragma unroll
            for (int dw = 0; dw < 3; ++dw) {
                int w = w0 + dw;
                if ((unsigned)w < 64u) s += row[w];
            }
        }
    }
    xp[((size_t)(n * 256 + c) << 12) + (t << 10) + (hd << 5) + wd] = s * (1.f / 9.f);
}

// ---------------------------------------------------------------------------
// conv_q: Q[n*16384+px][ic] = sum_c x[n][c][px]*theta_w[ic][c] + theta_b[ic]
// MFMA D[m=ic][n=px]; A = theta_w (native row-major), B = x (native col reads)
// ---------------------------------------------------------------------------
__launch_bounds__(256)
__global__ void k_convq(const float* __restrict__ x, const unsigned short* __restrict__ TW,
                        const float* __restrict__ tb, unsigned short* __restrict__ Q) {
    int tid = threadIdx.x, wid = tid >> 6, lane = tid & 63, quad = lane >> 4, l16 = lane & 15;
    int n = blockIdx.y;
    int px = blockIdx.x * 64 + wid * 16 + l16;
    const float* xb = x + ((size_t)n << 22) + px;
    floatx4 acc[8];
    #pragma unroll
    for (int i = 0; i < 8; ++i) acc[i] = (floatx4)0.f;
    for (int kc = 0; kc < 8; ++kc) {
        int cbase = kc * 32 + quad * 8;
        short8 b;
        #pragma unroll
        for (int j = 0; j < 8; ++j) b[j] = (short)f2bf(xb[(size_t)(cbase + j) << 14]);
        #pragma unroll
        for (int mt = 0; mt < 8; ++mt) {
            short8 a = *(const short8*)(TW + (mt * 16 + l16) * 256 + cbase);
            acc[mt] = MFMA16(a, b, acc[mt]);
        }
    }
    unsigned short* Qr = Q + ((((size_t)n << 14) + px) << 7);
    #pragma unroll
    for (int mt = 0; mt < 8; ++mt)
        #pragma unroll
        for (int r = 0; r < 4; ++r) {
            int ic = mt * 16 + quad * 4 + r;
            Qr[ic] = f2bf(acc[mt][r] + tb[ic]);
        }
}

// ---------------------------------------------------------------------------
// conv_kv: from pooled xp produce
//   K[n*4096+key][ic]  = phi conv + phi_b*frac(key)
//   Vt[n][ic][key]     = g conv + g_b*frac(key); rows 128..130 = grid; 131..159 = 0
// ---------------------------------------------------------------------------
__launch_bounds__(256)
__global__ void k_convkv(const float* __restrict__ xp,
                         const unsigned short* __restrict__ PW, const float* __restrict__ pb,
                         const unsigned short* __restrict__ GW, const float* __restrict__ gb,
                         unsigned short* __restrict__ K, unsigned short* __restrict__ Vt) {
    int tid = threadIdx.x, wid = tid >> 6, lane = tid & 63, quad = lane >> 4, l16 = lane & 15;
    int n = blockIdx.y;
    int k0 = blockIdx.x * 64;
    int key = k0 + wid * 16 + l16;
    const float* xb = xp + ((size_t)n << 20) + key;
    floatx4 ka[8], va[8];
    #pragma unroll
    for (int i = 0; i < 8; ++i) { ka[i] = (floatx4)0.f; va[i] = (floatx4)0.f; }
    for (int kc = 0; kc < 8; ++kc) {
        int cbase = kc * 32 + quad * 8;
        short8 b;
        #pragma unroll
        for (int j = 0; j < 8; ++j) b[j] = (short)f2bf(xb[(size_t)(cbase + j) << 12]);
        #pragma unroll
        for (int mt = 0; mt < 8; ++mt) {
            short8 ap = *(const short8*)(PW + (mt * 16 + l16) * 256 + cbase);
            ka[mt] = MFMA16(ap, b, ka[mt]);
            short8 ag = *(const short8*)(GW + (mt * 16 + l16) * 256 + cbase);
            va[mt] = MFMA16(ag, b, va[mt]);
        }
    }
    int hd = (key >> 5) & 31, wdd = key & 31;
    float frac = ((hd == 0) ? 2.f : 3.f) * ((wdd == 0) ? 2.f : 3.f) * (1.f / 9.f);
    unsigned short* Kr = K + ((((size_t)n << 12) + key) << 7);
    #pragma unroll
    for (int mt = 0; mt < 8; ++mt)
        #pragma unroll
        for (int r = 0; r < 4; ++r) {
            int ic = mt * 16 + quad * 4 + r;
            Kr[ic] = f2bf(ka[mt][r] + pb[ic] * frac);
            Vt[(((size_t)n * 160 + ic) << 12) + key] = f2bf(va[mt][r] + gb[ic] * frac);
        }
    // grid channels (128..130) and zero pad rows (131..159) for this key tile
    #pragma unroll
    for (int it = 0; it < 8; ++it) {
        int e = it * 256 + tid;                 // 32 rows x 64 keys
        int row = 128 + (e >> 6);
        int kk = k0 + (e & 63);
        int t = kk >> 10, hh = (kk >> 5) & 31, ww = kk & 31;
        unsigned short v = 0;
        if (row == 128) v = f2bf(((float)t * (1.f / 1.5f) - 1.f) * 0.1f);
        else if (row == 129) v = f2bf((float)hh * (1.f / 15.5f) - 1.f);
        else if (row == 130) v = f2bf((float)ww * (1.f / 7.75f) - 2.f);
        Vt[(((size_t)n * 160 + row) << 12) + kk] = v;
    }
}

// ---------------------------------------------------------------------------
// flash attention: y[p][0..143] = softmax(Q K^T) V  (cols 144..159 zeroed)
// WG = 64 queries (16/wave); key chunks of 64 staged in LDS
// ---------------------------------------------------------------------------
__launch_bounds__(256)
__global__ void k_attn(const unsigned short* __restrict__ Q, const unsigned short* __restrict__ K,
                       const unsigned short* __restrict__ Vt, unsigned short* __restrict__ Y) {
    __shared__ short Klds[64][136];   // key x c, +8 pad -> 2-way bank aliasing only
    __shared__ short Vlds[160][72];   // vdim x key, +8 pad
    __shared__ short Plds[4][16][72]; // per-wave P: query x key, +8 pad
    int tid = threadIdx.x, wid = tid >> 6, lane = tid & 63, quad = lane >> 4, l16 = lane & 15;
    int n = blockIdx.y;
    int q0 = blockIdx.x * 64 + wid * 16;

    const unsigned short* Qr = Q + ((((size_t)n << 14) + q0 + l16) << 7);
    short8 qf[4];
    #pragma unroll
    for (int kc = 0; kc < 4; ++kc) qf[kc] = *(const short8*)(Qr + kc * 32 + quad * 8);

    floatx4 O[9];
    #pragma unroll
    for (int t = 0; t < 9; ++t) O[t] = (floatx4)0.f;
    float m_[4], l_[4];
    #pragma unroll
    for (int r = 0; r < 4; ++r) { m_[r] = -1e30f; l_[r] = 0.f; }

    const unsigned short* Kb = K + (((size_t)n << 12) << 7);
    const unsigned short* Vb = Vt + ((size_t)n * 160 << 12);

    for (int kb = 0; kb < 64; ++kb) {
        int k0 = kb * 64;
        __syncthreads();
        #pragma unroll
        for (int it = 0; it < 4; ++it) {              // K chunk 64x128
            int idx = it * 256 + tid;
            int row = idx >> 4, c8 = idx & 15;
            *(short8*)&Klds[row][c8 * 8] = *(const short8*)(Kb + (size_t)(k0 + row) * 128 + c8 * 8);
        }
        #pragma unroll
        for (int it = 0; it < 5; ++it) {              // V chunk 160x64
            int idx = it * 256 + tid;
            int row = idx >> 3, c8 = idx & 7;
            *(short8*)&Vlds[row][c8 * 8] = *(const short8*)(Vb + ((size_t)row << 12) + k0 + c8 * 8);
        }
        __syncthreads();

        // S = Q K^T  (16 queries x 64 keys)
        floatx4 s[4];
        #pragma unroll
        for (int kt = 0; kt < 4; ++kt) {
            s[kt] = (floatx4)0.f;
            #pragma unroll
            for (int kc = 0; kc < 4; ++kc) {
                short8 kf = *(const short8*)&Klds[kt * 16 + l16][kc * 32 + quad * 8];
                s[kt] = MFMA16(qf[kc], kf, s[kt]);
            }
        }
        // online softmax (rows live on 16-lane groups sharing quad)
        float alpha[4];
        #pragma unroll
        for (int r = 0; r < 4; ++r) {
            float v = fmaxf(fmaxf(s[0][r], s[1][r]), fmaxf(s[2][r], s[3][r]));
            v = fmaxf(v, __shfl_xor(v, 1)); v = fmaxf(v, __shfl_xor(v, 2));
            v = fmaxf(v, __shfl_xor(v, 4)); v = fmaxf(v, __shfl_xor(v, 8));
            float mn = fmaxf(m_[r], v);
            alpha[r] = __expf(m_[r] - mn);
            m_[r] = mn;
        }
        #pragma unroll
        for (int kt = 0; kt < 4; ++kt)
            #pragma unroll
            for (int r = 0; r < 4; ++r) s[kt][r] = __expf(s[kt][r] - m_[r]);
        #pragma unroll
        for (int r = 0; r < 4; ++r) {
            float sm = s[0][r] + s[1][r] + s[2][r] + s[3][r];
            sm += __shfl_xor(sm, 1); sm += __shfl_xor(sm, 2);
            sm += __shfl_xor(sm, 4); sm += __shfl_xor(sm, 8);
            l_[r] = l_[r] * alpha[r] + sm;
        }
        #pragma unroll
        for (int t = 0; t < 9; ++t) {
            floatx4 o = O[t];
            #pragma unroll
            for (int r = 0; r < 4; ++r) o[r] *= alpha[r];
            O[t] = o;
        }
        // P: C-layout -> A-layout via per-wave LDS round trip
        #pragma unroll
        for (int kt = 0; kt < 4; ++kt)
            #pragma unroll
            for (int r = 0; r < 4; ++r)
                Plds[wid][quad * 4 + r][kt * 16 + l16] = (short)f2bf(s[kt][r]);
        __builtin_amdgcn_s_waitcnt(0);   // drain ds_writes before dependent ds_reads
        #pragma unroll
        for (int kc2 = 0; kc2 < 2; ++kc2) {
            short8 pf = *(const short8*)&Plds[wid][l16][kc2 * 32 + quad * 8];
            #pragma unroll
            for (int t = 0; t < 9; ++t) {
                short8 vf = *(const short8*)&Vlds[t * 16 + l16][kc2 * 32 + quad * 8];
                O[t] = MFMA16(pf, vf, O[t]);
            }
        }
    }
    // epilogue: normalize and store y[p][160] bf16
    #pragma unroll
    for (int r = 0; r < 4; ++r) {
        float inv = 1.f / l_[r];
        size_t p = ((size_t)n << 14) + q0 + quad * 4 + r;
        unsigned short* yr = Y + p * 160;
        #pragma unroll
        for (int t = 0; t < 9; ++t) yr[t * 16 + l16] = f2bf(O[t][r] * inv);
        yr[144 + l16] = 0;
    }
}

// ---------------------------------------------------------------------------
// final conv: out[n][oc][px] = sum_{k<160} Wp[oc][k]*y[p][k] + W_b[oc]
// ---------------------------------------------------------------------------
__launch_bounds__(256)
__global__ void k_convf(const unsigned short* __restrict__ Y, const unsigned short* __restrict__ Wp,
                        const float* __restrict__ Wb, float* __restrict__ out) {
    int tid = threadIdx.x, wid = tid >> 6, lane = tid & 63, quad = lane >> 4, l16 = lane & 15;
    int n = blockIdx.y;
    int p0 = blockIdx.x * 64;
    floatx4 acc[4][4];
    #pragma unroll
    for (int i = 0; i < 4; ++i)
        #pragma unroll
        for (int j = 0; j < 4; ++j) acc[i][j] = (floatx4)0.f;
    const unsigned short* Yb = Y + (((size_t)n << 14) + p0) * 160;
    for (int kc = 0; kc < 5; ++kc) {
        int cb = kc * 32 + quad * 8;
        short8 bf[4];
        #pragma unroll
        for (int nt = 0; nt < 4; ++nt)
            bf[nt] = *(const short8*)(Yb + (size_t)(nt * 16 + l16) * 160 + cb);
        #pragma unroll
        for (int mt = 0; mt < 4; ++mt) {
            short8 a = *(const short8*)(Wp + (size_t)(wid * 64 + mt * 16 + l16) * 160 + cb);
            #pragma unroll
            for (int nt = 0; nt < 4; ++nt) acc[mt][nt] = MFMA16(a, bf[nt], acc[mt][nt]);
        }
    }
    #pragma unroll
    for (int mt = 0; mt < 4; ++mt)
        #pragma unroll
        for (int r = 0; r < 4; ++r) {
            int oc = wid * 64 + mt * 16 + quad * 4 + r;
            float bb = Wb[oc];
            float* orow = out + ((((size_t)n << 8) + oc) << 14) + p0;
            #pragma unroll
            for (int nt = 0; nt < 4; ++nt)
                orow[nt * 16 + l16] = acc[mt][nt][r] + bb;
        }
}

// ---------------------------------------------------------------------------
extern "C" void kernel_launch(void* const* d_in, const int* in_sizes, int n_in,
                              void* d_out, int out_size, void* d_ws, size_t ws_size,
                              hipStream_t stream) {
    (void)in_sizes; (void)n_in; (void)out_size; (void)ws_size;
    const float* x   = (const float*)d_in[0];
    const float* thw = (const float*)d_in[1];
    const float* thb = (const float*)d_in[2];
    const float* phw = (const float*)d_in[3];
    const float* phb = (const float*)d_in[4];
    const float* gw_ = (const float*)d_in[5];
    const float* gb_ = (const float*)d_in[6];
    const float* Ww  = (const float*)d_in[7];
    const float* Wb  = (const float*)d_in[8];
    float* out = (float*)d_out;

    char* ws = (char*)d_ws;
    size_t off = 0;
    auto alloc = [&](size_t b) { size_t o = off; off += (b + 255) & ~(size_t)255; return o; };
    unsigned short* TW = (unsigned short*)(ws + alloc(32768 * 2));
    unsigned short* PW = (unsigned short*)(ws + alloc(32768 * 2));
    unsigned short* GW = (unsigned short*)(ws + alloc(32768 * 2));
    unsigned short* Wp = (unsigned short*)(ws + alloc(40960 * 2));
    unsigned short* Qb = (unsigned short*)(ws + alloc((size_t)32768 * 128 * 2));
    unsigned short* Kb = (unsigned short*)(ws + alloc((size_t)8192 * 128 * 2));
    unsigned short* Vt = (unsigned short*)(ws + alloc((size_t)2 * 160 * 4096 * 2));
    unsigned short* Yb = (unsigned short*)(ws + alloc((size_t)32768 * 160 * 2));
    float*          xp = (float*)(ws + alloc((size_t)2 * 256 * 4096 * 4));

    k_prep<<<(139264 + 255) / 256, 256, 0, stream>>>(thw, phw, gw_, Ww, TW, PW, GW, Wp);
    k_pool<<<8192, 256, 0, stream>>>(x, xp);
    k_convq<<<dim3(256, 2), 256, 0, stream>>>(x, TW, thb, Qb);
    k_convkv<<<dim3(64, 2), 256, 0, stream>>>(xp, PW, phb, GW, gb_, Kb, Vt);
    k_attn<<<dim3(256, 2), 256, 0, stream>>>(Qb, Kb, Vt, Yb);
    k_convf<<<dim3(256, 2), 256, 0, stream>>>(Yb, Wp, Wb, out);
}

// Round 2
// 324.162 us; speedup vs baseline: 1.4692x; 1.4692x over previous
//
#include <hip/hip_runtime.h>
#include <stdint.h>

typedef short short8 __attribute__((ext_vector_type(8)));
typedef float floatx4 __attribute__((ext_vector_type(4)));
typedef float floatx16 __attribute__((ext_vector_type(16)));

#define MFMA16(a, b, c) __builtin_amdgcn_mfma_f32_16x16x32_bf16((a), (b), (c), 0, 0, 0)
#define MFMA32(a, b, c) __builtin_amdgcn_mfma_f32_32x32x16_bf16((a), (b), (c), 0, 0, 0)

__device__ __forceinline__ unsigned short f2bf(float f) {
    union { float f; unsigned u; } v; v.f = f;
    unsigned u = v.u;
    unsigned r = (u + 0x7FFFu + ((u >> 16) & 1u)) >> 16;
    return (unsigned short)r;
}
__device__ __forceinline__ unsigned pk2(float a, float b) {
    return (unsigned)f2bf(a) | ((unsigned)f2bf(b) << 16);
}

// ---------------------------------------------------------------------------
// prep: convert weights to bf16; pad W_w [256,131] -> [256,160] with zeros
// ---------------------------------------------------------------------------
__global__ void k_prep(const float* th, const float* ph, const float* gw, const float* Ww,
                       unsigned short* TW, unsigned short* PW, unsigned short* GW,
                       unsigned short* Wp) {
    int i = blockIdx.x * 256 + threadIdx.x;
    if (i < 32768) {
        TW[i] = f2bf(th[i]);
    } else if (i < 65536) {
        PW[i - 32768] = f2bf(ph[i - 32768]);
    } else if (i < 98304) {
        GW[i - 65536] = f2bf(gw[i - 65536]);
    } else if (i < 98304 + 256 * 160) {
        int j = i - 98304;
        int oc = j / 160, k = j - oc * 160;
        Wp[j] = (k < 131) ? f2bf(Ww[oc * 131 + k]) : (unsigned short)0;
    }
}

// ---------------------------------------------------------------------------
// pool: xp[n][c][t][hd][wd] = sum_{3x3 window, stride2, pad1}(x)/9
// ---------------------------------------------------------------------------
__global__ void k_pool(const float* __restrict__ x, float* __restrict__ xp) {
    int e = blockIdx.x * 256 + threadIdx.x;           // < 2*256*4096
    int wd = e & 31, hd = (e >> 5) & 31, t = (e >> 10) & 3, c = (e >> 12) & 255, n = e >> 20;
    const float* base = x + (((size_t)(n * 256 + c) * 4 + t) << 12);
    int h0 = 2 * hd - 1, w0 = 2 * wd - 1;
    float s = 0.f;
    #pragma unroll
    for (int dh = 0; dh < 3; ++dh) {
        int h = h0 + dh;
        if ((unsigned)h < 64u) {
            const float* row = base + h * 64;
            #pragma unroll
            for (int dw = 0; dw < 3; ++dw) {
                int w = w0 + dw;
                if ((unsigned)w < 64u) s += row[w];
            }
        }
    }
    xp[((size_t)(n * 256 + c) << 12) + (t << 10) + (hd << 5) + wd] = s * (1.f / 9.f);
}

// ---------------------------------------------------------------------------
// conv_q: Q[n*16384+px][ic] = sum_c x[n][c][px]*theta_w[ic][c] + theta_b[ic]
// ---------------------------------------------------------------------------
__launch_bounds__(256)
__global__ void k_convq(const float* __restrict__ x, const unsigned short* __restrict__ TW,
                        const float* __restrict__ tb, unsigned short* __restrict__ Q) {
    int tid = threadIdx.x, wid = tid >> 6, lane = tid & 63, quad = lane >> 4, l16 = lane & 15;
    int n = blockIdx.y;
    int px = blockIdx.x * 64 + wid * 16 + l16;
    const float* xb = x + ((size_t)n << 22) + px;
    floatx4 acc[8];
    #pragma unroll
    for (int i = 0; i < 8; ++i) acc[i] = (floatx4)0.f;
    for (int kc = 0; kc < 8; ++kc) {
        int cbase = kc * 32 + quad * 8;
        short8 b;
        #pragma unroll
        for (int j = 0; j < 8; ++j) b[j] = (short)f2bf(xb[(size_t)(cbase + j) << 14]);
        #pragma unroll
        for (int mt = 0; mt < 8; ++mt) {
            short8 a = *(const short8*)(TW + (mt * 16 + l16) * 256 + cbase);
            acc[mt] = MFMA16(a, b, acc[mt]);
        }
    }
    unsigned short* Qr = Q + ((((size_t)n << 14) + px) << 7);
    #pragma unroll
    for (int mt = 0; mt < 8; ++mt)
        #pragma unroll
        for (int r = 0; r < 4; ++r) {
            int ic = mt * 16 + quad * 4 + r;
            Qr[ic] = f2bf(acc[mt][r] + tb[ic]);
        }
}

// ---------------------------------------------------------------------------
// conv_kv: K[n*4096+key][ic] (phi), Vt[n][ic][key] (g; rows 128..130 grid, 131..159 = 0)
// ---------------------------------------------------------------------------
__launch_bounds__(256)
__global__ void k_convkv(const float* __restrict__ xp,
                         const unsigned short* __restrict__ PW, const float* __restrict__ pb,
                         const unsigned short* __restrict__ GW, const float* __restrict__ gb,
                         unsigned short* __restrict__ K, unsigned short* __restrict__ Vt) {
    int tid = threadIdx.x, wid = tid >> 6, lane = tid & 63, quad = lane >> 4, l16 = lane & 15;
    int n = blockIdx.y;
    int k0 = blockIdx.x * 64;
    int key = k0 + wid * 16 + l16;
    const float* xb = xp + ((size_t)n << 20) + key;
    floatx4 ka[8], va[8];
    #pragma unroll
    for (int i = 0; i < 8; ++i) { ka[i] = (floatx4)0.f; va[i] = (floatx4)0.f; }
    for (int kc = 0; kc < 8; ++kc) {
        int cbase = kc * 32 + quad * 8;
        short8 b;
        #pragma unroll
        for (int j = 0; j < 8; ++j) b[j] = (short)f2bf(xb[(size_t)(cbase + j) << 12]);
        #pragma unroll
        for (int mt = 0; mt < 8; ++mt) {
            short8 ap = *(const short8*)(PW + (mt * 16 + l16) * 256 + cbase);
            ka[mt] = MFMA16(ap, b, ka[mt]);
            short8 ag = *(const short8*)(GW + (mt * 16 + l16) * 256 + cbase);
            va[mt] = MFMA16(ag, b, va[mt]);
        }
    }
    int hd = (key >> 5) & 31, wdd = key & 31;
    float frac = ((hd == 0) ? 2.f : 3.f) * ((wdd == 0) ? 2.f : 3.f) * (1.f / 9.f);
    unsigned short* Kr = K + ((((size_t)n << 12) + key) << 7);
    #pragma unroll
    for (int mt = 0; mt < 8; ++mt)
        #pragma unroll
        for (int r = 0; r < 4; ++r) {
            int ic = mt * 16 + quad * 4 + r;
            Kr[ic] = f2bf(ka[mt][r] + pb[ic] * frac);
            Vt[(((size_t)n * 160 + ic) << 12) + key] = f2bf(va[mt][r] + gb[ic] * frac);
        }
    #pragma unroll
    for (int it = 0; it < 8; ++it) {
        int e = it * 256 + tid;                 // 32 rows x 64 keys
        int row = 128 + (e >> 6);
        int kk = k0 + (e & 63);
        int t = kk >> 10, hh = (kk >> 5) & 31, ww = kk & 31;
        unsigned short v = 0;
        if (row == 128) v = f2bf(((float)t * (1.f / 1.5f) - 1.f) * 0.1f);
        else if (row == 129) v = f2bf((float)hh * (1.f / 15.5f) - 1.f);
        else if (row == 130) v = f2bf((float)ww * (1.f / 7.75f) - 2.f);
        Vt[(((size_t)n * 160 + row) << 12) + kk] = v;
    }
}

// ---------------------------------------------------------------------------
// flash attention v2: 32x32x16 MFMA, transposed orientation.
//   S^T = K Q^T   (C col = query -> per-lane l, rows = keys -> b64 P writes)
//   O^T = V^T P^T (raw exp sums; no max tracking, fixed shift of 12)
// WG = 4 waves x 32 q = 128 queries; split-K = 2 (2048 keys/WG, 64-key chunks).
// Y stores RAW O^T (bf16), L stores raw l; conv-f combines splits & normalizes.
// ---------------------------------------------------------------------------
__launch_bounds__(256, 2)
__global__ void k_attn(const unsigned short* __restrict__ Q, const unsigned short* __restrict__ K,
                       const unsigned short* __restrict__ Vt, unsigned short* __restrict__ Y,
                       float* __restrict__ L) {
    __shared__ short Klds[64][136];   // key x c, +8 pad: conflict-free b128 phases
    __shared__ short Vlds[160][72];   // vdim x key, +8 pad
    __shared__ short Plds[4][32][40]; // per-wave P^T staging: q x key, +8 pad
    int tid = threadIdx.x, wid = tid >> 6, lane = tid & 63;
    int l32 = lane & 31, half = lane >> 5;
    int n = blockIdx.y, sp = blockIdx.z;
    int q0 = blockIdx.x * 128 + wid * 32;

    // Q B-fragments (persistent): qf[kc][j] = Q[q0+l32][kc*16 + half*8 + j]
    const unsigned short* Qr = Q + ((((size_t)n << 14) + q0 + l32) << 7);
    short8 qf[8];
    #pragma unroll
    for (int kc = 0; kc < 8; ++kc) qf[kc] = *(const short8*)(Qr + kc * 16 + half * 8);

    floatx16 O[5];
    #pragma unroll
    for (int t = 0; t < 5; ++t) O[t] = (floatx16)0.f;
    float lacc = 0.f;

    const unsigned short* Kb = K + (((size_t)n << 12) << 7);
    const unsigned short* Vb = Vt + ((size_t)n * 160 << 12);

    for (int it = 0; it < 32; ++it) {
        int k0 = sp * 2048 + it * 64;
        __syncthreads();
        #pragma unroll
        for (int i = 0; i < 4; ++i) {         // K chunk: 64 keys x 128 c
            int key = i * 16 + (tid >> 4), c8 = tid & 15;
            *(short8*)&Klds[key][c8 * 8] = *(const short8*)(Kb + (size_t)(k0 + key) * 128 + c8 * 8);
        }
        #pragma unroll
        for (int i = 0; i < 5; ++i) {         // V chunk: 160 vdim x 64 keys
            int row = i * 32 + (tid >> 3), c8 = tid & 7;
            *(short8*)&Vlds[row][c8 * 8] = *(const short8*)(Vb + ((size_t)row << 12) + k0 + c8 * 8);
        }
        __syncthreads();

        #pragma unroll
        for (int ks = 0; ks < 2; ++ks) {      // two 32-key subtiles
            floatx16 st = (floatx16)0.f;
            #pragma unroll
            for (int kc = 0; kc < 8; ++kc) {
                short8 kf = *(const short8*)&Klds[ks * 32 + l32][kc * 16 + half * 8];
                st = MFMA32(kf, qf[kc], st);
            }
            // p = exp(s - 12), accumulate raw row-sum per lane (col = this lane's q)
            float p[16];
            #pragma unroll
            for (int r = 0; r < 16; ++r) {
                p[r] = exp2f(fmaf(st[r], 1.44269504f, -17.3123404907f));
                lacc += p[r];
            }
            // pack P^T into LDS: regs r=4g..4g+3 are 4 consecutive keys -> b64
            #pragma unroll
            for (int g = 0; g < 4; ++g) {
                uint2 w;
                w.x = pk2(p[4 * g], p[4 * g + 1]);
                w.y = pk2(p[4 * g + 2], p[4 * g + 3]);
                *(uint2*)&Plds[wid][l32][8 * g + 4 * half] = w;
            }
            asm volatile("s_waitcnt lgkmcnt(0)" ::: "memory");
            #pragma unroll
            for (int kk = 0; kk < 2; ++kk) {
                short8 pf = *(const short8*)&Plds[wid][l32][kk * 16 + half * 8];
                #pragma unroll
                for (int vt = 0; vt < 5; ++vt) {
                    short8 vf = *(const short8*)&Vlds[vt * 32 + l32][ks * 32 + kk * 16 + half * 8];
                    O[vt] = MFMA32(vf, pf, O[vt]);
                }
            }
        }
    }
    // epilogue: raw l (both lane halves), raw O -> bf16
    float lt = lacc + __shfl_xor(lacc, 32);
    unsigned short* Yb = Y + ((((size_t)(sp * 2 + n) << 14) + q0 + l32) * 160);
    #pragma unroll
    for (int vt = 0; vt < 5; ++vt)
        #pragma unroll
        for (int g = 0; g < 4; ++g) {
            int vd = vt * 32 + 8 * g + 4 * half;
            uint2 w;
            w.x = pk2(O[vt][4 * g], O[vt][4 * g + 1]);
            w.y = pk2(O[vt][4 * g + 2], O[vt][4 * g + 3]);
            *(uint2*)(Yb + vd) = w;
        }
    if (lane < 32) L[(((size_t)(sp * 2 + n)) << 14) + q0 + lane] = lt;
}

// ---------------------------------------------------------------------------
// final conv + split combine + normalize:
// out[n][oc][p] = (sum_sp sum_k Wp[oc][k]*Y[sp][n][p][k]) / (L0[p]+L1[p]) + Wb[oc]
// ---------------------------------------------------------------------------
__launch_bounds__(256)
__global__ void k_convf(const unsigned short* __restrict__ Y, const float* __restrict__ L,
                        const unsigned short* __restrict__ Wp, const float* __restrict__ Wb,
                        float* __restrict__ out) {
    int tid = threadIdx.x, wid = tid >> 6, lane = tid & 63, quad = lane >> 4, l16 = lane & 15;
    int n = blockIdx.y;
    int p0 = blockIdx.x * 64;
    floatx4 acc[4][4];
    #pragma unroll
    for (int i = 0; i < 4; ++i)
        #pragma unroll
        for (int j = 0; j < 4; ++j) acc[i][j] = (floatx4)0.f;
    for (int kc = 0; kc < 5; ++kc) {
        int cb = kc * 32 + quad * 8;
        short8 a[4];
        #pragma unroll
        for (int mt = 0; mt < 4; ++mt)
            a[mt] = *(const short8*)(Wp + (size_t)(wid * 64 + mt * 16 + l16) * 160 + cb);
        #pragma unroll
        for (int sp = 0; sp < 2; ++sp) {
            const unsigned short* Yb = Y + ((((size_t)(sp * 2 + n)) << 14) + p0) * 160;
            #pragma unroll
            for (int nt = 0; nt < 4; ++nt) {
                short8 b = *(const short8*)(Yb + (size_t)(nt * 16 + l16) * 160 + cb);
                #pragma unroll
                for (int mt = 0; mt < 4; ++mt) acc[mt][nt] = MFMA16(a[mt], b, acc[mt][nt]);
            }
        }
    }
    float linv[4];
    #pragma unroll
    for (int nt = 0; nt < 4; ++nt) {
        int p = p0 + nt * 16 + l16;
        linv[nt] = 1.f / (L[(((size_t)n) << 14) + p] + L[(((size_t)(2 + n)) << 14) + p]);
    }
    #pragma unroll
    for (int mt = 0; mt < 4; ++mt)
        #pragma unroll
        for (int r = 0; r < 4; ++r) {
            int oc = wid * 64 + mt * 16 + quad * 4 + r;
            float bb = Wb[oc];
            float* orow = out + ((((size_t)n << 8) + oc) << 14) + p0;
            #pragma unroll
            for (int nt = 0; nt < 4; ++nt)
                orow[nt * 16 + l16] = acc[mt][nt][r] * linv[nt] + bb;
        }
}

// ---------------------------------------------------------------------------
extern "C" void kernel_launch(void* const* d_in, const int* in_sizes, int n_in,
                              void* d_out, int out_size, void* d_ws, size_t ws_size,
                              hipStream_t stream) {
    (void)in_sizes; (void)n_in; (void)out_size; (void)ws_size;
    const float* x   = (const float*)d_in[0];
    const float* thw = (const float*)d_in[1];
    const float* thb = (const float*)d_in[2];
    const float* phw = (const float*)d_in[3];
    const float* phb = (const float*)d_in[4];
    const float* gw_ = (const float*)d_in[5];
    const float* gb_ = (const float*)d_in[6];
    const float* Ww  = (const float*)d_in[7];
    const float* Wb  = (const float*)d_in[8];
    float* out = (float*)d_out;

    char* ws = (char*)d_ws;
    size_t off = 0;
    auto alloc = [&](size_t b) { size_t o = off; off += (b + 255) & ~(size_t)255; return o; };
    unsigned short* TW = (unsigned short*)(ws + alloc(32768 * 2));
    unsigned short* PW = (unsigned short*)(ws + alloc(32768 * 2));
    unsigned short* GW = (unsigned short*)(ws + alloc(32768 * 2));
    unsigned short* Wp = (unsigned short*)(ws + alloc(40960 * 2));
    unsigned short* Qb = (unsigned short*)(ws + alloc((size_t)32768 * 128 * 2));
    unsigned short* Kb = (unsigned short*)(ws + alloc((size_t)8192 * 128 * 2));
    unsigned short* Vt = (unsigned short*)(ws + alloc((size_t)2 * 160 * 4096 * 2));
    float*          Lb = (float*)(ws + alloc((size_t)2 * 2 * 16384 * 4));
    // Y: [split][n][p][160], 21 MB; xp (8.4 MB) aliases split-1's half (pool/convkv
    // finish before attn writes Y on the same stream).
    unsigned short* Yb = (unsigned short*)(ws + alloc((size_t)2 * 2 * 16384 * 160 * 2));
    float*          xp = (float*)((char*)Yb + (size_t)2 * 16384 * 160 * 2);

    k_prep<<<(139264 + 255) / 256, 256, 0, stream>>>(thw, phw, gw_, Ww, TW, PW, GW, Wp);
    k_pool<<<8192, 256, 0, stream>>>(x, xp);
    k_convq<<<dim3(256, 2), 256, 0, stream>>>(x, TW, thb, Qb);
    k_convkv<<<dim3(64, 2), 256, 0, stream>>>(xp, PW, phb, GW, gb_, Kb, Vt);
    k_attn<<<dim3(128, 2, 2), 256, 0, stream>>>(Qb, Kb, Vt, Yb, Lb);
    k_convf<<<dim3(256, 2), 256, 0, stream>>>(Yb, Lb, Wp, Wb, out);
}

// Round 3
// 273.135 us; speedup vs baseline: 1.7437x; 1.1868x over previous
//
#include <hip/hip_runtime.h>
#include <stdint.h>

typedef short short8 __attribute__((ext_vector_type(8)));
typedef float floatx4 __attribute__((ext_vector_type(4)));
typedef float floatx16 __attribute__((ext_vector_type(16)));
typedef unsigned uint4v __attribute__((ext_vector_type(4)));

#define MFMA16(a, b, c) __builtin_amdgcn_mfma_f32_16x16x32_bf16((a), (b), (c), 0, 0, 0)
#define MFMA32(a, b, c) __builtin_amdgcn_mfma_f32_32x32x16_bf16((a), (b), (c), 0, 0, 0)

__device__ __forceinline__ unsigned short f2bf(float f) {
    union { float f; unsigned u; } v; v.f = f;
    unsigned u = v.u;
    unsigned r = (u + 0x7FFFu + ((u >> 16) & 1u)) >> 16;
    return (unsigned short)r;
}
// fast pack: round-half-up both floats to bf16, pack lo|hi<<16 in one v_perm
__device__ __forceinline__ unsigned pkfast(float lo, float hi) {
    unsigned a = __float_as_uint(lo) + 0x8000u;
    unsigned b = __float_as_uint(hi) + 0x8000u;
    return __builtin_amdgcn_perm(b, a, 0x07060302u);
}

// ---------------------------------------------------------------------------
// prep: convert weights to bf16; pad W_w [256,131] -> [256,160] with zeros
// ---------------------------------------------------------------------------
__global__ void k_prep(const float* th, const float* ph, const float* gw, const float* Ww,
                       unsigned short* TW, unsigned short* PW, unsigned short* GW,
                       unsigned short* Wp) {
    int i = blockIdx.x * 256 + threadIdx.x;
    if (i < 32768) {
        TW[i] = f2bf(th[i]);
    } else if (i < 65536) {
        PW[i - 32768] = f2bf(ph[i - 32768]);
    } else if (i < 98304) {
        GW[i - 65536] = f2bf(gw[i - 65536]);
    } else if (i < 98304 + 256 * 160) {
        int j = i - 98304;
        int oc = j / 160, k = j - oc * 160;
        Wp[j] = (k < 131) ? f2bf(Ww[oc * 131 + k]) : (unsigned short)0;
    }
}

// ---------------------------------------------------------------------------
// pool: xp[n][c][t][hd][wd] = sum_{3x3 window, stride2, pad1}(x)/9
// ---------------------------------------------------------------------------
__global__ void k_pool(const float* __restrict__ x, float* __restrict__ xp) {
    int e = blockIdx.x * 256 + threadIdx.x;           // < 2*256*4096
    int wd = e & 31, hd = (e >> 5) & 31, t = (e >> 10) & 3, c = (e >> 12) & 255, n = e >> 20;
    const float* base = x + (((size_t)(n * 256 + c) * 4 + t) << 12);
    int h0 = 2 * hd - 1, w0 = 2 * wd - 1;
    float s = 0.f;
    #pragma unroll
    for (int dh = 0; dh < 3; ++dh) {
        int h = h0 + dh;
        if ((unsigned)h < 64u) {
            const float* row = base + h * 64;
            #pragma unroll
            for (int dw = 0; dw < 3; ++dw) {
                int w = w0 + dw;
                if ((unsigned)w < 64u) s += row[w];
            }
        }
    }
    xp[((size_t)(n * 256 + c) << 12) + (t << 10) + (hd << 5) + wd] = s * (1.f / 9.f);
}

// ---------------------------------------------------------------------------
// conv_q: Q[n*16384+px][ic] = sum_c x[n][c][px]*theta_w[ic][c] + theta_b[ic]
// ---------------------------------------------------------------------------
__launch_bounds__(256)
__global__ void k_convq(const float* __restrict__ x, const unsigned short* __restrict__ TW,
                        const float* __restrict__ tb, unsigned short* __restrict__ Q) {
    int tid = threadIdx.x, wid = tid >> 6, lane = tid & 63, quad = lane >> 4, l16 = lane & 15;
    int n = blockIdx.y;
    int px = blockIdx.x * 64 + wid * 16 + l16;
    const float* xb = x + ((size_t)n << 22) + px;
    floatx4 acc[8];
    #pragma unroll
    for (int i = 0; i < 8; ++i) acc[i] = (floatx4)0.f;
    for (int kc = 0; kc < 8; ++kc) {
        int cbase = kc * 32 + quad * 8;
        short8 b;
        #pragma unroll
        for (int j = 0; j < 8; ++j) b[j] = (short)f2bf(xb[(size_t)(cbase + j) << 14]);
        #pragma unroll
        for (int mt = 0; mt < 8; ++mt) {
            short8 a = *(const short8*)(TW + (mt * 16 + l16) * 256 + cbase);
            acc[mt] = MFMA16(a, b, acc[mt]);
        }
    }
    unsigned short* Qr = Q + ((((size_t)n << 14) + px) << 7);
    #pragma unroll
    for (int mt = 0; mt < 8; ++mt)
        #pragma unroll
        for (int r = 0; r < 4; ++r) {
            int ic = mt * 16 + quad * 4 + r;
            Qr[ic] = f2bf(acc[mt][r] + tb[ic]);
        }
}

// ---------------------------------------------------------------------------
// conv_kv: K[n*4096+key][ic] (phi), Vt[n][ic][key] (g; rows 128..130 grid, 131..159 = 0)
// ---------------------------------------------------------------------------
__launch_bounds__(256)
__global__ void k_convkv(const float* __restrict__ xp,
                         const unsigned short* __restrict__ PW, const float* __restrict__ pb,
                         const unsigned short* __restrict__ GW, const float* __restrict__ gb,
                         unsigned short* __restrict__ K, unsigned short* __restrict__ Vt) {
    int tid = threadIdx.x, wid = tid >> 6, lane = tid & 63, quad = lane >> 4, l16 = lane & 15;
    int n = blockIdx.y;
    int k0 = blockIdx.x * 64;
    int key = k0 + wid * 16 + l16;
    const float* xb = xp + ((size_t)n << 20) + key;
    floatx4 ka[8], va[8];
    #pragma unroll
    for (int i = 0; i < 8; ++i) { ka[i] = (floatx4)0.f; va[i] = (floatx4)0.f; }
    for (int kc = 0; kc < 8; ++kc) {
        int cbase = kc * 32 + quad * 8;
        short8 b;
        #pragma unroll
        for (int j = 0; j < 8; ++j) b[j] = (short)f2bf(xb[(size_t)(cbase + j) << 12]);
        #pragma unroll
        for (int mt = 0; mt < 8; ++mt) {
            short8 ap = *(const short8*)(PW + (mt * 16 + l16) * 256 + cbase);
            ka[mt] = MFMA16(ap, b, ka[mt]);
            short8 ag = *(const short8*)(GW + (mt * 16 + l16) * 256 + cbase);
            va[mt] = MFMA16(ag, b, va[mt]);
        }
    }
    int hd = (key >> 5) & 31, wdd = key & 31;
    float frac = ((hd == 0) ? 2.f : 3.f) * ((wdd == 0) ? 2.f : 3.f) * (1.f / 9.f);
    unsigned short* Kr = K + ((((size_t)n << 12) + key) << 7);
    #pragma unroll
    for (int mt = 0; mt < 8; ++mt)
        #pragma unroll
        for (int r = 0; r < 4; ++r) {
            int ic = mt * 16 + quad * 4 + r;
            Kr[ic] = f2bf(ka[mt][r] + pb[ic] * frac);
            Vt[(((size_t)n * 160 + ic) << 12) + key] = f2bf(va[mt][r] + gb[ic] * frac);
        }
    #pragma unroll
    for (int it = 0; it < 8; ++it) {
        int e = it * 256 + tid;                 // 32 rows x 64 keys
        int row = 128 + (e >> 6);
        int kk = k0 + (e & 63);
        int t = kk >> 10, hh = (kk >> 5) & 31, ww = kk & 31;
        unsigned short v = 0;
        if (row == 128) v = f2bf(((float)t * (1.f / 1.5f) - 1.f) * 0.1f);
        else if (row == 129) v = f2bf((float)hh * (1.f / 15.5f) - 1.f);
        else if (row == 130) v = f2bf((float)ww * (1.f / 7.75f) - 2.f);
        Vt[(((size_t)n * 160 + row) << 12) + kk] = v;
    }
}

// ---------------------------------------------------------------------------
// flash attention v3: 32x32x16, transposed; register-prefetch staging;
// P transpose via shfl_xor(32) + cndmask (no LDS round trip, no lgkm drain).
//   S^T = K Q^T ; p = exp(s-12); O^T += V^T P^T (raw sums, split-K combine later)
// ---------------------------------------------------------------------------
__launch_bounds__(256, 2)
__global__ void k_attn(const unsigned short* __restrict__ Q, const unsigned short* __restrict__ K,
                       const unsigned short* __restrict__ Vt, unsigned short* __restrict__ Y,
                       float* __restrict__ L) {
    __shared__ short Klds[64][136];   // key x c
    __shared__ short Vlds[160][72];   // vdim x key
    int tid = threadIdx.x, wid = tid >> 6, lane = tid & 63;
    int l32 = lane & 31, half = lane >> 5;
    int n = blockIdx.y, sp = blockIdx.z;
    int q0 = blockIdx.x * 128 + wid * 32;

    const unsigned short* Qr = Q + ((((size_t)n << 14) + q0 + l32) << 7);
    short8 qf[8];
    #pragma unroll
    for (int kc = 0; kc < 8; ++kc) qf[kc] = *(const short8*)(Qr + kc * 16 + half * 8);

    floatx16 O[5];
    #pragma unroll
    for (int t = 0; t < 5; ++t) O[t] = (floatx16)0.f;
    float lacc = 0.f;

    // per-thread staging addresses (chunk-relative)
    int krow = tid >> 4, kcol = (tid & 15) * 8;      // K: 16 rows/pass x 128 c
    int vrow = tid >> 3, vcol = (tid & 7) * 8;       // V: 32 rows/pass x 64 keys
    const unsigned short* kptr = K + ((((size_t)n << 12) + sp * 2048 + krow) << 7) + kcol;
    const unsigned short* vptr = Vt + ((size_t)(n * 160 + vrow) << 12) + sp * 2048 + vcol;

    short8 kpre[4], vpre[5];
    #pragma unroll
    for (int i = 0; i < 4; ++i) kpre[i] = *(const short8*)(kptr + (size_t)i * 16 * 128);
    #pragma unroll
    for (int i = 0; i < 5; ++i) vpre[i] = *(const short8*)(vptr + ((size_t)i * 32 << 12));

    for (int it = 0; it < 32; ++it) {
        __syncthreads();                      // prior compute done reading LDS
        #pragma unroll
        for (int i = 0; i < 4; ++i) *(short8*)&Klds[i * 16 + krow][kcol] = kpre[i];
        #pragma unroll
        for (int i = 0; i < 5; ++i) *(short8*)&Vlds[i * 32 + vrow][vcol] = vpre[i];
        __syncthreads();
        if (it < 31) {                        // issue next chunk's loads now
            const unsigned short* kp = kptr + (size_t)(it + 1) * 64 * 128;
            const unsigned short* vp = vptr + (size_t)(it + 1) * 64;
            #pragma unroll
            for (int i = 0; i < 4; ++i) kpre[i] = *(const short8*)(kp + (size_t)i * 16 * 128);
            #pragma unroll
            for (int i = 0; i < 5; ++i) vpre[i] = *(const short8*)(vp + ((size_t)i * 32 << 12));
        }

        #pragma unroll
        for (int ks = 0; ks < 2; ++ks) {      // two 32-key subtiles
            floatx16 st = (floatx16)0.f;
            #pragma unroll
            for (int kc = 0; kc < 8; ++kc) {
                short8 kf = *(const short8*)&Klds[ks * 32 + l32][kc * 16 + half * 8];
                st = MFMA32(kf, qf[kc], st);
            }
            // p = exp(s-12); pack pairs; lane r holds key (r&3)+8*(r>>2)+4*half
            unsigned u[8];
            #pragma unroll
            for (int a = 0; a < 4; ++a) {
                float p0 = exp2f(fmaf(st[4 * a + 0], 1.44269504f, -17.3123404907f));
                float p1 = exp2f(fmaf(st[4 * a + 1], 1.44269504f, -17.3123404907f));
                float p2 = exp2f(fmaf(st[4 * a + 2], 1.44269504f, -17.3123404907f));
                float p3 = exp2f(fmaf(st[4 * a + 3], 1.44269504f, -17.3123404907f));
                lacc += (p0 + p1) + (p2 + p3);
                u[2 * a] = pkfast(p0, p1);
                u[2 * a + 1] = pkfast(p2, p3);
            }
            unsigned xu[8];
            #pragma unroll
            for (int g = 0; g < 8; ++g) xu[g] = (unsigned)__shfl_xor((int)u[g], 32);
            // assemble B-operand fragments of P^T (keys kk*16+half*8+0..7, col=q)
            uint4v pw0, pw1;
            pw0[0] = half ? xu[2] : u[0];
            pw0[1] = half ? xu[3] : u[1];
            pw0[2] = half ? u[2] : xu[0];
            pw0[3] = half ? u[3] : xu[1];
            pw1[0] = half ? xu[6] : u[4];
            pw1[1] = half ? xu[7] : u[5];
            pw1[2] = half ? u[6] : xu[4];
            pw1[3] = half ? u[7] : xu[5];
            short8 pf0 = __builtin_bit_cast(short8, pw0);
            short8 pf1 = __builtin_bit_cast(short8, pw1);
            #pragma unroll
            for (int vt = 0; vt < 5; ++vt) {
                short8 vf0 = *(const short8*)&Vlds[vt * 32 + l32][ks * 32 + half * 8];
                O[vt] = MFMA32(vf0, pf0, O[vt]);
                short8 vf1 = *(const short8*)&Vlds[vt * 32 + l32][ks * 32 + 16 + half * 8];
                O[vt] = MFMA32(vf1, pf1, O[vt]);
            }
        }
    }
    // epilogue: raw l (both halves), raw O -> bf16
    float lt = lacc + __shfl_xor(lacc, 32);
    unsigned short* Yb = Y + ((((size_t)(sp * 2 + n) << 14) + q0 + l32) * 160);
    #pragma unroll
    for (int vt = 0; vt < 5; ++vt)
        #pragma unroll
        for (int g = 0; g < 4; ++g) {
            int vd = vt * 32 + 8 * g + 4 * half;
            uint2 w;
            w.x = pkfast(O[vt][4 * g], O[vt][4 * g + 1]);
            w.y = pkfast(O[vt][4 * g + 2], O[vt][4 * g + 3]);
            *(uint2*)(Yb + vd) = w;
        }
    if (lane < 32) L[(((size_t)(sp * 2 + n)) << 14) + q0 + lane] = lt;
}

// ---------------------------------------------------------------------------
// final conv + split combine + normalize:
// out[n][oc][p] = (sum_sp sum_k Wp[oc][k]*Y[sp][n][p][k]) / (L0[p]+L1[p]) + Wb[oc]
// ---------------------------------------------------------------------------
__launch_bounds__(256)
__global__ void k_convf(const unsigned short* __restrict__ Y, const float* __restrict__ L,
                        const unsigned short* __restrict__ Wp, const float* __restrict__ Wb,
                        float* __restrict__ out) {
    int tid = threadIdx.x, wid = tid >> 6, lane = tid & 63, quad = lane >> 4, l16 = lane & 15;
    int n = blockIdx.y;
    int p0 = blockIdx.x * 64;
    floatx4 acc[4][4];
    #pragma unroll
    for (int i = 0; i < 4; ++i)
        #pragma unroll
        for (int j = 0; j < 4; ++j) acc[i][j] = (floatx4)0.f;
    for (int kc = 0; kc < 5; ++kc) {
        int cb = kc * 32 + quad * 8;
        short8 a[4];
        #pragma unroll
        for (int mt = 0; mt < 4; ++mt)
            a[mt] = *(const short8*)(Wp + (size_t)(wid * 64 + mt * 16 + l16) * 160 + cb);
        #pragma unroll
        for (int sp = 0; sp < 2; ++sp) {
            const unsigned short* Yb = Y + ((((size_t)(sp * 2 + n)) << 14) + p0) * 160;
            #pragma unroll
            for (int nt = 0; nt < 4; ++nt) {
                short8 b = *(const short8*)(Yb + (size_t)(nt * 16 + l16) * 160 + cb);
                #pragma unroll
                for (int mt = 0; mt < 4; ++mt) acc[mt][nt] = MFMA16(a[mt], b, acc[mt][nt]);
            }
        }
    }
    float linv[4];
    #pragma unroll
    for (int nt = 0; nt < 4; ++nt) {
        int p = p0 + nt * 16 + l16;
        linv[nt] = 1.f / (L[(((size_t)n) << 14) + p] + L[(((size_t)(2 + n)) << 14) + p]);
    }
    #pragma unroll
    for (int mt = 0; mt < 4; ++mt)
        #pragma unroll
        for (int r = 0; r < 4; ++r) {
            int oc = wid * 64 + mt * 16 + quad * 4 + r;
            float bb = Wb[oc];
            float* orow = out + ((((size_t)n << 8) + oc) << 14) + p0;
            #pragma unroll
            for (int nt = 0; nt < 4; ++nt)
                orow[nt * 16 + l16] = acc[mt][nt][r] * linv[nt] + bb;
        }
}

// ---------------------------------------------------------------------------
extern "C" void kernel_launch(void* const* d_in, const int* in_sizes, int n_in,
                              void* d_out, int out_size, void* d_ws, size_t ws_size,
                              hipStream_t stream) {
    (void)in_sizes; (void)n_in; (void)out_size; (void)ws_size;
    const float* x   = (const float*)d_in[0];
    const float* thw = (const float*)d_in[1];
    const float* thb = (const float*)d_in[2];
    const float* phw = (const float*)d_in[3];
    const float* phb = (const float*)d_in[4];
    const float* gw_ = (const float*)d_in[5];
    const float* gb_ = (const float*)d_in[6];
    const float* Ww  = (const float*)d_in[7];
    const float* Wb  = (const float*)d_in[8];
    float* out = (float*)d_out;

    char* ws = (char*)d_ws;
    size_t off = 0;
    auto alloc = [&](size_t b) { size_t o = off; off += (b + 255) & ~(size_t)255; return o; };
    unsigned short* TW = (unsigned short*)(ws + alloc(32768 * 2));
    unsigned short* PW = (unsigned short*)(ws + alloc(32768 * 2));
    unsigned short* GW = (unsigned short*)(ws + alloc(32768 * 2));
    unsigned short* Wp = (unsigned short*)(ws + alloc(40960 * 2));
    unsigned short* Qb = (unsigned short*)(ws + alloc((size_t)32768 * 128 * 2));
    unsigned short* Kb = (unsigned short*)(ws + alloc((size_t)8192 * 128 * 2));
    unsigned short* Vt = (unsigned short*)(ws + alloc((size_t)2 * 160 * 4096 * 2));
    float*          Lb = (float*)(ws + alloc((size_t)2 * 2 * 16384 * 4));
    // Y: [split][n][p][160], 21 MB; xp (8.4 MB) aliases split-1's half (pool/convkv
    // finish before attn writes Y on the same stream).
    unsigned short* Yb = (unsigned short*)(ws + alloc((size_t)2 * 2 * 16384 * 160 * 2));
    float*          xp = (float*)((char*)Yb + (size_t)2 * 16384 * 160 * 2);

    k_prep<<<(139264 + 255) / 256, 256, 0, stream>>>(thw, phw, gw_, Ww, TW, PW, GW, Wp);
    k_pool<<<8192, 256, 0, stream>>>(x, xp);
    k_convq<<<dim3(256, 2), 256, 0, stream>>>(x, TW, thb, Qb);
    k_convkv<<<dim3(64, 2), 256, 0, stream>>>(xp, PW, phb, GW, gb_, Kb, Vt);
    k_attn<<<dim3(128, 2, 2), 256, 0, stream>>>(Qb, Kb, Vt, Yb, Lb);
    k_convf<<<dim3(256, 2), 256, 0, stream>>>(Yb, Lb, Wp, Wb, out);
}